// Round 3
// baseline (73.132 us; speedup 1.0000x reference)
//
#include <hip/hip_runtime.h>
#include <math.h>

// 2D Gaussian splatting, tile-based with order-preserving culling. Two kernels:
//   prep_kernel   : one pass over N gaussians -> 16-float records in d_ws:
//                   [mx, my, ia', 2ib', ic', lop, r, g, b, -, -, -, x0, x1, y0, y1]
//                   conic folded with -0.5*log2(e) and log2(opacity) so the hot
//                   loop's only transcendental is exp2. bbox at q<=QMAX.
//   render_kernel : 512 blocks, one 32x16 tile each (256 thr, 2 px/thread).
//                   Stage the 16 KB record table to LDS (L2-hot broadcast),
//                   ballot+prefix-compact bbox hits in gaussian order (compositing
//                   is order-dependent), then front-to-back over ~6 survivors.
//                   Skipped gaussians have alpha < e^-15 -> error <= N*3e-7.

#define BLOCK 256
#define QMAX 30.0f
#define ALPHA_CLIP 0.999f
#define LOG2E 1.4426950408889634f

__global__ void prep_kernel(const float* __restrict__ xyz,
                            const float* __restrict__ rot,
                            const float* __restrict__ scal,
                            const float* __restrict__ feat,
                            const float* __restrict__ opac,
                            const int* __restrict__ dH,
                            const int* __restrict__ dW,
                            float* __restrict__ gp, int N) {
    int i = blockIdx.x * blockDim.x + threadIdx.x;
    if (i >= N) return;
    const float Wf = (float)(*dW), Hf = (float)(*dH);
    const float mx = (xyz[2*i]   * 0.5f + 0.5f) * Wf;
    const float my = (xyz[2*i+1] * 0.5f + 0.5f) * Hf;
    const float r  = rot[i];
    const float theta = (1.0f / (1.0f + expf(-r))) * 6.283185307179586f;
    const float sd0 = 1.0f / (fabsf(scal[2*i])   + 1e-6f);
    const float sd1 = 1.0f / (fabsf(scal[2*i+1]) + 1e-6f);
    const float s0 = sd0 * sd0, s1 = sd1 * sd1;
    const float c = cosf(theta), s = sinf(theta);
    const float A  = c*c*s0 + s*s*s1;       // Sigma_xx
    const float B  = c*s*(s0 - s1);
    const float Cc = s*s*s0 + c*c*s1;       // Sigma_yy
    const float det = A*Cc - B*B + 1e-12f;
    const float inv = 1.0f / det;
    const float kk = -0.5f * LOG2E;
    const float rx = sqrtf(QMAX * A);       // max |dx| on the q=QMAX ellipse
    const float ry = sqrtf(QMAX * Cc);
    float* rec = &gp[i * 16];
    rec[0]  = mx;
    rec[1]  = my;
    rec[2]  = Cc * inv * kk;
    rec[3]  = -B * inv * 2.0f * kk;
    rec[4]  = A  * inv * kk;
    rec[5]  = log2f(opac[i]);
    rec[6]  = feat[3*i+0];
    rec[7]  = feat[3*i+1];
    rec[8]  = feat[3*i+2];
    rec[9]  = 0.f; rec[10] = 0.f; rec[11] = 0.f;
    rec[12] = mx - rx;
    rec[13] = mx + rx;
    rec[14] = my - ry;
    rec[15] = my + ry;
}

__global__ __launch_bounds__(BLOCK) void render_kernel(
    const float* __restrict__ gp,
    const float* __restrict__ bg,
    const int* __restrict__ dW,
    float* __restrict__ out,
    int N, int P)
{
    __shared__ float sg[BLOCK * 16];   // one chunk of records (16 KB)
    __shared__ int   list[BLOCK];
    __shared__ int   wcnt[BLOCK / 64];
    __shared__ int   sM;

    const int t = threadIdx.x;
    const int W = *dW;                           // wave-uniform
    const int tiles_x = W >> 5;                  // 32-wide, 16-tall tiles
    const int tx0 = (blockIdx.x % tiles_x) << 5;
    const int ty0 = (blockIdx.x / tiles_x) << 4;

    const float fx0 = (float)tx0, fx1 = (float)(tx0 + 32);
    const float fy0 = (float)ty0, fy1 = (float)(ty0 + 16);

    const float gxp  = fx0 + (float)(t & 31) + 0.5f;  // this thread's pixel x
    const float gyp0 = fy0 + (float)(t >> 5) + 0.5f;  // row 0 of 2 (stride 8)

    float T[2]  = {1.f, 1.f};
    float ar[2] = {0.f, 0.f}, ag[2] = {0.f, 0.f}, ab[2] = {0.f, 0.f};

    for (int c0 = 0; c0 < N; c0 += BLOCK) {
        const int i = c0 + t;
        bool pred = false;
        if (i < N) {
            // stage this gaussian's full record (4 coalesced dwordx4) and test bbox
            const float4* src = (const float4*)&gp[i * 16];
            float4 r0 = src[0], r1 = src[1], r2 = src[2], r3 = src[3];
            float4* dst = (float4*)&sg[t * 16];
            dst[0] = r0; dst[1] = r1; dst[2] = r2; dst[3] = r3;
            pred = (r3.y >= fx0) & (r3.x <= fx1) &     // x1>=fx0 && x0<=fx1
                   (r3.w >= fy0) & (r3.z <= fy1);      // y1>=fy0 && y0<=fy1
        }

        const unsigned long long m = __ballot(pred);
        const int lane = t & 63, wid = t >> 6;
        if (lane == 0) wcnt[wid] = __popcll(m);
        __syncthreads();                         // records + wcnt visible
        int off = 0;
        for (int w = 0; w < wid; ++w) off += wcnt[w];
        if (pred)
            list[off + __popcll(m & ((1ull << lane) - 1ull))] = t;
        if (t == 0) sM = wcnt[0] + wcnt[1] + wcnt[2] + wcnt[3];
        __syncthreads();                         // list + sM visible
        const int M = sM;

        for (int j = 0; j < M; ++j) {
            const float* rec = &sg[list[j] * 16];          // broadcast reads
            const float4 g0 = *(const float4*)rec;         // mx,my,ia',2ib'
            const float4 g1 = *(const float4*)(rec + 4);   // ic',lop,r,g
            const float  cb = rec[8];
            const float dx = gxp - g0.x;
            const float q0 = fmaf(g0.z * dx, dx, g1.y);
            const float bx = g0.w * dx;
#pragma unroll
            for (int k = 0; k < 2; ++k) {
                const float dy = (gyp0 + 8.0f * (float)k) - g0.y;
                const float ea = fmaf(dy, fmaf(g1.x, dy, bx), q0);
                const float alpha = fminf(exp2f(ea), ALPHA_CLIP);
                const float w = alpha * T[k];
                ar[k] = fmaf(w, g1.z, ar[k]);
                ag[k] = fmaf(w, g1.w, ag[k]);
                ab[k] = fmaf(w, cb, ab[k]);
                T[k] -= w;
            }
        }
        __syncthreads();                         // before next chunk reuses sg
    }

    const float b0 = bg[0], b1 = bg[1], b2 = bg[2];
    const int px = tx0 + (t & 31);
#pragma unroll
    for (int k = 0; k < 2; ++k) {
        const int py = ty0 + (t >> 5) + 8 * k;
        const int p = py * W + px;
        if (p < P) {
            out[p]         = fmaf(b0, T[k], ar[k]);
            out[P + p]     = fmaf(b1, T[k], ag[k]);
            out[2*P + p]   = fmaf(b2, T[k], ab[k]);
        }
    }
}

extern "C" void kernel_launch(void* const* d_in, const int* in_sizes, int n_in,
                              void* d_out, int out_size, void* d_ws, size_t ws_size,
                              hipStream_t stream) {
    const float* xyz  = (const float*)d_in[0];
    const float* rot  = (const float*)d_in[1];
    const float* scal = (const float*)d_in[2];
    const float* feat = (const float*)d_in[3];
    const float* opac = (const float*)d_in[4];
    const float* bg   = (const float*)d_in[5];
    const int*   dH   = (const int*)d_in[6];
    const int*   dW   = (const int*)d_in[7];
    float* out = (float*)d_out;
    float* gp  = (float*)d_ws;

    const int N = in_sizes[0] / 2;   // 256
    const int P = out_size / 3;      // H*W; tiles are 32x16 = 512 px

    prep_kernel<<<(N + 255) / 256, 256, 0, stream>>>(xyz, rot, scal, feat, opac,
                                                     dH, dW, gp, N);
    const int blocks = (P + 511) / 512;    // W%32==0, H%16==0 for this problem
    render_kernel<<<blocks, BLOCK, 0, stream>>>(gp, bg, dW, out, N, P);
}